// Round 1
// baseline (6166.140 us; speedup 1.0000x reference)
//
#include <hip/hip_runtime.h>
#include <math.h>

#define Hd 1024
#define Td 64
#define Vd 32000
#define Ld 256
#define Cd 32

// workspace float offsets
static const size_t OFF_ENCX  = 0;         // 64*1024
static const size_t OFF_DECX  = 65536;     // 64*1024
static const size_t OFF_GENC  = 131072;    // 64*4096
static const size_t OFF_GDEC  = 393216;    // 64*4096
static const size_t OFF_BSE   = 655360;    // 4096
static const size_t OFF_BSD   = 659456;    // 4096
static const size_t OFF_TEN   = 663552;    // 32
static const size_t OFF_HA    = 663584;    // 1024 (ping)
static const size_t OFF_HB    = 664608;    // 1024 (pong)
static const size_t OFF_IN288 = 665632;    // 288
static const size_t OFF_MEANS = 665920;    // 256
static const size_t OFF_LOGVS = 666176;    // 256
static const size_t OFF_HALL  = 666432;    // 64*1024
static const size_t OFF_RMAX  = 731968;    // 64
static const size_t OFF_RLSE  = 732032;    // 64
static const size_t OFF_BAR   = 732096;    // 2 unsigned

__device__ __forceinline__ float sigm(float x) { return 1.f / (1.f + expf(-x)); }

// ---------------- prep: gathers, bias sums, h0 init, barrier reset ----------
__global__ void prep_kernel(const int* __restrict__ word, const int* __restrict__ tense,
                            const float* __restrict__ tense_emb,
                            const float* __restrict__ enc_emb, const float* __restrict__ dec_emb,
                            const float* __restrict__ enc_bih, const float* __restrict__ enc_bhh,
                            const float* __restrict__ dec_bih, const float* __restrict__ dec_bhh,
                            float* __restrict__ ws) {
  int i = blockIdx.x * blockDim.x + threadIdx.x;
  int tens = tense[0];
  if (i < Td * Hd) {
    int t = i >> 10, hh = i & 1023;
    ws[OFF_ENCX + i] = enc_emb[(size_t)word[t] * Hd + hh];
    int tok = (t == 0) ? 0 : word[t - 1];           // SOS = 0
    float v = dec_emb[(size_t)tok * Hd + hh];
    ws[OFF_DECX + i] = v > 0.f ? v : 0.f;           // relu
  }
  if (i < 4096) {
    ws[OFF_BSE + i] = enc_bih[i] + enc_bhh[i];
    ws[OFF_BSD + i] = dec_bih[i] + dec_bhh[i];
  }
  if (i < Hd) ws[OFF_HA + i] = (i < Hd - Cd) ? 0.f : tense_emb[tens * Cd + (i - (Hd - Cd))];
  if (i < Cd) ws[OFF_TEN + i] = tense_emb[tens * Cd + i];
  if (i < 2) ((unsigned*)(ws + OFF_BAR))[i] = 0u;
}

// ---------------- tiled fp32 GEMM: out[t][r] = sum_k W[r][k]*x[t][k] + bias[r]
// x: [64][1024], W: [R][1024]; block tile 64t x 128r, thread tile 8x8.
__global__ __launch_bounds__(128) void gemm64_kernel(
    const float* __restrict__ W, const float* __restrict__ x,
    const float* __restrict__ bias, float* __restrict__ out, int R) {
  __shared__ float xs[64][65];
  __shared__ float wsh[128][65];
  int tid = threadIdx.x;
  int rbase = blockIdx.x * 128;
  int a = tid >> 4;    // 0..7  -> t tile
  int b = tid & 15;    // 0..15 -> r tile
  float acc[8][8];
#pragma unroll
  for (int i = 0; i < 8; ++i)
#pragma unroll
    for (int q = 0; q < 8; ++q) acc[i][q] = 0.f;

  for (int kc = 0; kc < 1024; kc += 64) {
    for (int i = tid; i < 64 * 16; i += 128) {
      int row = i >> 4, kk = (i & 15) << 2;
      const float4 v = *(const float4*)(x + (size_t)row * 1024 + kc + kk);
      xs[row][kk] = v.x; xs[row][kk + 1] = v.y; xs[row][kk + 2] = v.z; xs[row][kk + 3] = v.w;
    }
    for (int i = tid; i < 128 * 16; i += 128) {
      int row = i >> 4, kk = (i & 15) << 2;
      const float4 v = *(const float4*)(W + (size_t)(rbase + row) * 1024 + kc + kk);
      wsh[row][kk] = v.x; wsh[row][kk + 1] = v.y; wsh[row][kk + 2] = v.z; wsh[row][kk + 3] = v.w;
    }
    __syncthreads();
#pragma unroll 4
    for (int kk = 0; kk < 64; ++kk) {
      float xv[8], wv[8];
#pragma unroll
      for (int i = 0; i < 8; ++i) xv[i] = xs[a * 8 + i][kk];
#pragma unroll
      for (int q = 0; q < 8; ++q) wv[q] = wsh[b * 8 + q][kk];
#pragma unroll
      for (int i = 0; i < 8; ++i)
#pragma unroll
        for (int q = 0; q < 8; ++q) acc[i][q] = fmaf(xv[i], wv[q], acc[i][q]);
    }
    __syncthreads();
  }
#pragma unroll
  for (int i = 0; i < 8; ++i) {
    int t = a * 8 + i;
#pragma unroll
    for (int q = 0; q < 8; ++q) {
      int r = rbase + b * 8 + q;
      out[(size_t)t * R + r] = acc[i][q] + bias[r];
    }
  }
}

// ---------------- device-wide barrier (sense via generation counter) --------
__device__ __forceinline__ void gridbar(unsigned* bar, unsigned nblk) {
  __threadfence();                 // release my writes to device scope
  __syncthreads();
  if (threadIdx.x == 0) {
    unsigned g = __hip_atomic_load(bar + 1, __ATOMIC_RELAXED, __HIP_MEMORY_SCOPE_AGENT);
    unsigned a = __hip_atomic_fetch_add(bar, 1u, __ATOMIC_ACQ_REL, __HIP_MEMORY_SCOPE_AGENT);
    if (a + 1u == nblk) {
      __hip_atomic_store(bar, 0u, __ATOMIC_RELAXED, __HIP_MEMORY_SCOPE_AGENT);
      __hip_atomic_store(bar + 1, g + 1u, __ATOMIC_RELEASE, __HIP_MEMORY_SCOPE_AGENT);
    } else {
      while (__hip_atomic_load(bar + 1, __ATOMIC_RELAXED, __HIP_MEMORY_SCOPE_AGENT) == g) {
        __builtin_amdgcn_s_sleep(2);
      }
    }
  }
  __syncthreads();
  __threadfence();                 // acquire: invalidate stale caches
}

// ---------------- persistent sequential kernel: enc LSTM -> latent -> dec LSTM
// 256 blocks x 256 threads; wave j owns hidden column j (4 gate rows in regs).
__global__ __launch_bounds__(256, 1) void seq_kernel(
    const float* __restrict__ enc_Whh, const float* __restrict__ dec_Whh,
    const float* __restrict__ W_mean, const float* __restrict__ b_mean,
    const float* __restrict__ W_var, const float* __restrict__ b_var,
    const float* __restrict__ W_l2h, const float* __restrict__ b_l2h,
    const float* __restrict__ eps, float* __restrict__ ws, float* __restrict__ dout) {
  __shared__ float hs[Hd];
  const int tid = threadIdx.x;
  const int lane = tid & 63;
  const int j = blockIdx.x * 4 + (tid >> 6);   // 0..1023
  const unsigned nblk = gridDim.x;

  float* Genc  = ws + OFF_GENC;
  float* Gdec  = ws + OFF_GDEC;
  float* h_a   = ws + OFF_HA;
  float* h_b   = ws + OFF_HB;
  float* in288 = ws + OFF_IN288;
  float* means = ws + OFF_MEANS;
  float* logvs = ws + OFF_LOGVS;
  float* h_all = ws + OFF_HALL;
  float* ten   = ws + OFF_TEN;
  unsigned* bar = (unsigned*)(ws + OFF_BAR);

  // recurrent weights -> registers: we[r][i] = Whh[r*H+j][lane + 64*i]
  float we[4][16], wd[4][16];
#pragma unroll
  for (int r = 0; r < 4; ++r) {
    const size_t ro = (size_t)(r * Hd + j) * Hd + lane;
#pragma unroll
    for (int i = 0; i < 16; ++i) {
      we[r][i] = enc_Whh[ro + 64 * i];
      wd[r][i] = dec_Whh[ro + 64 * i];
    }
  }

  // ---- encoder ----
  float c_reg = 0.f;
  for (int t = 0; t < Td; ++t) {
    const float* hrd = (t & 1) ? h_b : h_a;
#pragma unroll
    for (int q = 0; q < 4; ++q) hs[tid + 256 * q] = hrd[tid + 256 * q];
    __syncthreads();
    float p0 = 0.f, p1 = 0.f, p2 = 0.f, p3 = 0.f;
#pragma unroll
    for (int i = 0; i < 16; ++i) {
      float hv = hs[lane + 64 * i];
      p0 = fmaf(we[0][i], hv, p0);
      p1 = fmaf(we[1][i], hv, p1);
      p2 = fmaf(we[2][i], hv, p2);
      p3 = fmaf(we[3][i], hv, p3);
    }
#pragma unroll
    for (int off = 32; off; off >>= 1) {
      p0 += __shfl_xor(p0, off, 64); p1 += __shfl_xor(p1, off, 64);
      p2 += __shfl_xor(p2, off, 64); p3 += __shfl_xor(p3, off, 64);
    }
    float gi = Genc[t * 4096 + j] + p0;
    float gf = Genc[t * 4096 + Hd + j] + p1;
    float gg = Genc[t * 4096 + 2 * Hd + j] + p2;
    float go = Genc[t * 4096 + 3 * Hd + j] + p3;
    c_reg = sigm(gf) * c_reg + sigm(gi) * tanhf(gg);
    float hval = sigm(go) * tanhf(c_reg);
    float* hwr = (t & 1) ? h_a : h_b;
    if (lane == 0) hwr[j] = hval;
    gridbar(bar, nblk);
  }

  // final encoder h lives in h_a (T even). Stage it.
#pragma unroll
  for (int q = 0; q < 4; ++q) hs[tid + 256 * q] = h_a[tid + 256 * q];
  __syncthreads();

  // ---- mean / logvar ----
  if (j < 512) {
    const float* Wrow = (j < 256) ? (W_mean + (size_t)j * Hd) : (W_var + (size_t)(j - 256) * Hd);
    float p = 0.f;
#pragma unroll
    for (int i = 0; i < 16; ++i) p = fmaf(Wrow[lane + 64 * i], hs[lane + 64 * i], p);
#pragma unroll
    for (int off = 32; off; off >>= 1) p += __shfl_xor(p, off, 64);
    if (lane == 0) {
      if (j < 256) { float v = p + b_mean[j]; means[j] = v; dout[2048064 + j] = v; }
      else { int r = j - 256; float v = p + b_var[r]; logvs[r] = v; dout[2048320 + r] = v; }
    }
  }
  gridbar(bar, nblk);

  // ---- latent + [latent|tense] ----
  if (j < 256 && lane == 0) in288[j] = means[j] + eps[j] * expf(0.5f * logvs[j]);
  if (j == 512 && lane < 32) in288[256 + lane] = ten[lane];
  gridbar(bar, nblk);

  // ---- dec_h0 = [latent|tense] @ W_l2h.T + b_l2h -> h_a ----
  {
    float p = 0.f;
#pragma unroll
    for (int m = 0; m < 5; ++m) {
      int k = lane + 64 * m;
      if (k < 288) p = fmaf(W_l2h[(size_t)j * 288 + k], in288[k], p);
    }
#pragma unroll
    for (int off = 32; off; off >>= 1) p += __shfl_xor(p, off, 64);
    if (lane == 0) h_a[j] = p + b_l2h[j];
  }
  gridbar(bar, nblk);

  // ---- decoder ----
  c_reg = 0.f;
  for (int t = 0; t < Td; ++t) {
    const float* hrd = (t & 1) ? h_b : h_a;
#pragma unroll
    for (int q = 0; q < 4; ++q) hs[tid + 256 * q] = hrd[tid + 256 * q];
    __syncthreads();
    float p0 = 0.f, p1 = 0.f, p2 = 0.f, p3 = 0.f;
#pragma unroll
    for (int i = 0; i < 16; ++i) {
      float hv = hs[lane + 64 * i];
      p0 = fmaf(wd[0][i], hv, p0);
      p1 = fmaf(wd[1][i], hv, p1);
      p2 = fmaf(wd[2][i], hv, p2);
      p3 = fmaf(wd[3][i], hv, p3);
    }
#pragma unroll
    for (int off = 32; off; off >>= 1) {
      p0 += __shfl_xor(p0, off, 64); p1 += __shfl_xor(p1, off, 64);
      p2 += __shfl_xor(p2, off, 64); p3 += __shfl_xor(p3, off, 64);
    }
    float gi = Gdec[t * 4096 + j] + p0;
    float gf = Gdec[t * 4096 + Hd + j] + p1;
    float gg = Gdec[t * 4096 + 2 * Hd + j] + p2;
    float go = Gdec[t * 4096 + 3 * Hd + j] + p3;
    c_reg = sigm(gf) * c_reg + sigm(gi) * tanhf(gg);
    float hval = sigm(go) * tanhf(c_reg);
    float* hwr = (t & 1) ? h_a : h_b;
    if (lane == 0) { hwr[j] = hval; h_all[t * Hd + j] = hval; }
    gridbar(bar, nblk);
  }
}

// ---------------- per-row max/argmax/log-sum-exp over vocab ------------------
__global__ __launch_bounds__(256) void rowstats_kernel(const float* __restrict__ logits,
                                                       float* __restrict__ rmax,
                                                       float* __restrict__ rlse,
                                                       float* __restrict__ pred) {
  int t = blockIdx.x, tid = threadIdx.x;
  __shared__ float sm[256];
  __shared__ int si[256];
  float m = -INFINITY; int mi = 0x7fffffff;
  for (int v = tid; v < Vd; v += 256) {
    float x = logits[(size_t)t * Vd + v];
    if (x > m) { m = x; mi = v; }
  }
  sm[tid] = m; si[tid] = mi;
  __syncthreads();
  for (int s = 128; s > 0; s >>= 1) {
    if (tid < s) {
      float om = sm[tid + s]; int oi = si[tid + s];
      if (om > sm[tid] || (om == sm[tid] && oi < si[tid])) { sm[tid] = om; si[tid] = oi; }
    }
    __syncthreads();
  }
  float rm = sm[0]; int ri = si[0];
  __syncthreads();
  float s = 0.f;
  for (int v = tid; v < Vd; v += 256) s += expf(logits[(size_t)t * Vd + v] - rm);
  sm[tid] = s;
  __syncthreads();
  for (int st = 128; st > 0; st >>= 1) {
    if (tid < st) sm[tid] += sm[tid + st];
    __syncthreads();
  }
  if (tid == 0) { rmax[t] = rm; rlse[t] = logf(sm[0]); pred[t] = (float)ri; }
}

// ---------------- in-place log_softmax finalize ------------------------------
__global__ void finalize_kernel(float* __restrict__ out, const float* __restrict__ rmax,
                                const float* __restrict__ rlse) {
  int i = blockIdx.x * blockDim.x + threadIdx.x;   // over 512000 float4s
  if (i < 512000) {
    int base = i * 4;
    int t = base / Vd;                              // Vd % 4 == 0 -> same t for all 4
    float m = rmax[t] + rlse[t];
    float4* p = (float4*)(out + 64 + base);
    float4 v = *p;
    v.x -= m; v.y -= m; v.z -= m; v.w -= m;
    *p = v;
  }
}

extern "C" void kernel_launch(void* const* d_in, const int* in_sizes, int n_in,
                              void* d_out, int out_size, void* d_ws, size_t ws_size,
                              hipStream_t stream) {
  (void)in_sizes; (void)n_in; (void)out_size; (void)ws_size;
  const int* word       = (const int*)d_in[0];
  const int* tense      = (const int*)d_in[1];
  // d_in[2] = use_teacher_forcing (unused; reference always teacher-forces)
  const float* tense_emb = (const float*)d_in[3];
  const float* enc_emb   = (const float*)d_in[4];
  const float* enc_Wih   = (const float*)d_in[5];
  const float* enc_Whh   = (const float*)d_in[6];
  const float* enc_bih   = (const float*)d_in[7];
  const float* enc_bhh   = (const float*)d_in[8];
  const float* W_mean    = (const float*)d_in[9];
  const float* b_mean    = (const float*)d_in[10];
  const float* W_var     = (const float*)d_in[11];
  const float* b_var     = (const float*)d_in[12];
  const float* W_l2h     = (const float*)d_in[13];
  const float* b_l2h     = (const float*)d_in[14];
  const float* dec_emb   = (const float*)d_in[15];
  const float* dec_Wih   = (const float*)d_in[16];
  const float* dec_Whh   = (const float*)d_in[17];
  const float* dec_bih   = (const float*)d_in[18];
  const float* dec_bhh   = (const float*)d_in[19];
  const float* W_out     = (const float*)d_in[20];
  const float* b_out     = (const float*)d_in[21];
  const float* eps       = (const float*)d_in[22];
  float* out = (float*)d_out;
  float* ws  = (float*)d_ws;

  prep_kernel<<<256, 256, 0, stream>>>(word, tense, tense_emb, enc_emb, dec_emb,
                                       enc_bih, enc_bhh, dec_bih, dec_bhh, ws);
  // batched input-side GEMMs: G = x @ Wih.T + (bih + bhh)
  gemm64_kernel<<<32, 128, 0, stream>>>(enc_Wih, ws + OFF_ENCX, ws + OFF_BSE, ws + OFF_GENC, 4096);
  gemm64_kernel<<<32, 128, 0, stream>>>(dec_Wih, ws + OFF_DECX, ws + OFF_BSD, ws + OFF_GDEC, 4096);

  {
    const float* a0 = enc_Whh; const float* a1 = dec_Whh;
    const float* a2 = W_mean;  const float* a3 = b_mean;
    const float* a4 = W_var;   const float* a5 = b_var;
    const float* a6 = W_l2h;   const float* a7 = b_l2h;
    const float* a8 = eps;     float* a9 = ws; float* a10 = out;
    void* args[] = {&a0, &a1, &a2, &a3, &a4, &a5, &a6, &a7, &a8, &a9, &a10};
    hipLaunchCooperativeKernel((void*)seq_kernel, dim3(256), dim3(256), args, 0, stream);
  }

  // logits for all 64 steps in one GEMM (raw logits into d_out[64..])
  gemm64_kernel<<<250, 128, 0, stream>>>(W_out, ws + OFF_HALL, b_out, out + 64, 32000);
  rowstats_kernel<<<64, 256, 0, stream>>>(out + 64, ws + OFF_RMAX, ws + OFF_RLSE, out);
  finalize_kernel<<<2000, 256, 0, stream>>>(out, ws + OFF_RMAX, ws + OFF_RLSE);
}

// Round 2
// 649.417 us; speedup vs baseline: 9.4949x; 9.4949x over previous
//
#include <hip/hip_runtime.h>
#include <math.h>

#define Hd 1024
#define Td 64
#define Vd 32000

// ---- workspace float offsets ----
static const size_t OFF_ENCX  = 0;         // 64*1024
static const size_t OFF_DECX  = 65536;     // 64*1024
static const size_t OFF_GENC  = 131072;    // 64*4096
static const size_t OFF_GDEC  = 393216;    // 64*4096
static const size_t OFF_BSE   = 655360;    // 4096
static const size_t OFF_BSD   = 659456;    // 4096
static const size_t OFF_TEN   = 663552;    // 32
static const size_t OFF_HALL  = 663584;    // 64*1024
static const size_t OFF_RMAX  = 729120;    // 64
static const size_t OFF_RLSE  = 729184;    // 64
static const size_t OFF_HBUF  = 729248;    // 130*1024 float2 (flagged h exchange)
static const size_t OFF_MEANF = 995488;    // 512 float2 (flagged mean/logvar)

#define FLAG_HI 0x3f800000u

__device__ __forceinline__ float sigm(float x) { return 1.f / (1.f + expf(-x)); }

__device__ __forceinline__ void st_flagged(unsigned long long* p, float v) {
  unsigned long long u = ((unsigned long long)FLAG_HI << 32) |
                         (unsigned long long)__float_as_uint(v);
  __hip_atomic_store(p, u, __ATOMIC_RELAXED, __HIP_MEMORY_SCOPE_AGENT);
}

__device__ __forceinline__ float ld_spin(const unsigned long long* p) {
  for (;;) {
    unsigned long long u =
        __hip_atomic_load((unsigned long long*)p, __ATOMIC_RELAXED, __HIP_MEMORY_SCOPE_AGENT);
    if ((unsigned)(u >> 32) == FLAG_HI) return __uint_as_float((unsigned)u);
    __builtin_amdgcn_s_sleep(1);
  }
}

// poll 4 flagged entries per thread from one step buffer, stage full h into LDS
__device__ __forceinline__ void stage_h(const unsigned long long* p, float* hs, int tid) {
  unsigned long long u0 = 0, u1 = 0, u2 = 0, u3 = 0;
  bool d0 = false, d1 = false, d2 = false, d3 = false;
  do {
    if (!d0) { u0 = __hip_atomic_load((unsigned long long*)(p + tid),       __ATOMIC_RELAXED, __HIP_MEMORY_SCOPE_AGENT); d0 = (unsigned)(u0 >> 32) == FLAG_HI; }
    if (!d1) { u1 = __hip_atomic_load((unsigned long long*)(p + tid + 256), __ATOMIC_RELAXED, __HIP_MEMORY_SCOPE_AGENT); d1 = (unsigned)(u1 >> 32) == FLAG_HI; }
    if (!d2) { u2 = __hip_atomic_load((unsigned long long*)(p + tid + 512), __ATOMIC_RELAXED, __HIP_MEMORY_SCOPE_AGENT); d2 = (unsigned)(u2 >> 32) == FLAG_HI; }
    if (!d3) { u3 = __hip_atomic_load((unsigned long long*)(p + tid + 768), __ATOMIC_RELAXED, __HIP_MEMORY_SCOPE_AGENT); d3 = (unsigned)(u3 >> 32) == FLAG_HI; }
    if (d0 && d1 && d2 && d3) break;
    __builtin_amdgcn_s_sleep(1);
  } while (true);
  __syncthreads();   // everyone done reading previous hs
  hs[tid]       = __uint_as_float((unsigned)u0);
  hs[tid + 256] = __uint_as_float((unsigned)u1);
  hs[tid + 512] = __uint_as_float((unsigned)u2);
  hs[tid + 768] = __uint_as_float((unsigned)u3);
  __syncthreads();
}

// ---------------- prep: gathers, bias sums, flag-buffer init ----------------
__global__ void prep_kernel(const int* __restrict__ word, const int* __restrict__ tense,
                            const float* __restrict__ tense_emb,
                            const float* __restrict__ enc_emb, const float* __restrict__ dec_emb,
                            const float* __restrict__ enc_bih, const float* __restrict__ enc_bhh,
                            const float* __restrict__ dec_bih, const float* __restrict__ dec_bhh,
                            float* __restrict__ ws) {
  int gid = blockIdx.x * blockDim.x + threadIdx.x;
  int gsz = gridDim.x * blockDim.x;
  int tens = tense[0];
  for (int i = gid; i < Td * Hd; i += gsz) {
    int t = i >> 10, hh = i & 1023;
    ws[OFF_ENCX + i] = enc_emb[(size_t)word[t] * Hd + hh];
    int tok = (t == 0) ? 0 : word[t - 1];        // SOS = 0
    float v = dec_emb[(size_t)tok * Hd + hh];
    ws[OFF_DECX + i] = v > 0.f ? v : 0.f;        // relu
  }
  for (int i = gid; i < 4096; i += gsz) {
    ws[OFF_BSE + i] = enc_bih[i] + enc_bhh[i];
    ws[OFF_BSD + i] = dec_bih[i] + dec_bhh[i];
  }
  for (int i = gid; i < 32; i += gsz) ws[OFF_TEN + i] = tense_emb[tens * 32 + i];
  float2* hb = (float2*)(ws + OFF_HBUF);
  for (int i = gid; i < 130 * 1024; i += gsz) {
    int s = i >> 10, j = i & 1023;
    float2 v;
    if (s == 0) {
      v.x = (j < Hd - 32) ? 0.f : tense_emb[tens * 32 + (j - (Hd - 32))];
      v.y = 1.0f;
    } else {
      v.x = 0.f; v.y = 0.f;
    }
    hb[i] = v;
  }
  float2* mf = (float2*)(ws + OFF_MEANF);
  for (int i = gid; i < 512; i += gsz) mf[i] = make_float2(0.f, 0.f);
}

// ---------------- fp32 GEMM body: out[t][r] = x[t]·W[r] + bias[r] -----------
// tile 64t x 64r per block, 256 threads, 4x4 per thread, K=1024
__device__ __forceinline__ void gemm_body(const float* __restrict__ W,
                                          const float* __restrict__ x,
                                          const float* __restrict__ bias,
                                          float* __restrict__ out, int R, int rbase) {
  __shared__ float xs[64][65];
  __shared__ float wsh[64][65];
  const int tid = threadIdx.x;
  const int a = tid >> 4;              // 0..15 -> t group of 4
  const int b = tid & 15;              // 0..15 -> r group of 4
  const int srow = tid >> 2;           // 0..63 staging row
  const int scol = (tid & 3) * 16;     // 0,16,32,48
  float acc[4][4];
#pragma unroll
  for (int i = 0; i < 4; ++i)
#pragma unroll
    for (int q = 0; q < 4; ++q) acc[i][q] = 0.f;

  for (int kc = 0; kc < 1024; kc += 64) {
    const float4* gx = (const float4*)(x + (size_t)srow * 1024 + kc + scol);
    const float4* gw = (const float4*)(W + (size_t)(rbase + srow) * 1024 + kc + scol);
    float4 vx0 = gx[0], vx1 = gx[1], vx2 = gx[2], vx3 = gx[3];
    float4 vw0 = gw[0], vw1 = gw[1], vw2 = gw[2], vw3 = gw[3];
    __syncthreads();   // previous tile fully consumed
    float* xr = &xs[srow][scol];
    xr[0]=vx0.x; xr[1]=vx0.y; xr[2]=vx0.z; xr[3]=vx0.w;
    xr[4]=vx1.x; xr[5]=vx1.y; xr[6]=vx1.z; xr[7]=vx1.w;
    xr[8]=vx2.x; xr[9]=vx2.y; xr[10]=vx2.z; xr[11]=vx2.w;
    xr[12]=vx3.x; xr[13]=vx3.y; xr[14]=vx3.z; xr[15]=vx3.w;
    float* wr = &wsh[srow][scol];
    wr[0]=vw0.x; wr[1]=vw0.y; wr[2]=vw0.z; wr[3]=vw0.w;
    wr[4]=vw1.x; wr[5]=vw1.y; wr[6]=vw1.z; wr[7]=vw1.w;
    wr[8]=vw2.x; wr[9]=vw2.y; wr[10]=vw2.z; wr[11]=vw2.w;
    wr[12]=vw3.x; wr[13]=vw3.y; wr[14]=vw3.z; wr[15]=vw3.w;
    __syncthreads();
#pragma unroll 8
    for (int kk = 0; kk < 64; ++kk) {
      float xv[4], wv[4];
#pragma unroll
      for (int i = 0; i < 4; ++i) xv[i] = xs[a * 4 + i][kk];
#pragma unroll
      for (int q = 0; q < 4; ++q) wv[q] = wsh[b * 4 + q][kk];
#pragma unroll
      for (int i = 0; i < 4; ++i)
#pragma unroll
        for (int q = 0; q < 4; ++q) acc[i][q] = fmaf(xv[i], wv[q], acc[i][q]);
    }
  }
#pragma unroll
  for (int i = 0; i < 4; ++i) {
    int t = a * 4 + i;
#pragma unroll
    for (int q = 0; q < 4; ++q) {
      int r = rbase + b * 4 + q;
      out[(size_t)t * R + r] = acc[i][q] + bias[r];
    }
  }
}

__global__ __launch_bounds__(256) void gemm_kernel(const float* __restrict__ W,
                                                   const float* __restrict__ x,
                                                   const float* __restrict__ bias,
                                                   float* __restrict__ out, int R) {
  gemm_body(W, x, bias, out, R, blockIdx.x * 64);
}

__global__ __launch_bounds__(256) void gemm_dual_kernel(
    const float* __restrict__ W0, const float* __restrict__ x0,
    const float* __restrict__ b0, float* __restrict__ o0,
    const float* __restrict__ W1, const float* __restrict__ x1,
    const float* __restrict__ b1, float* __restrict__ o1) {
  if (blockIdx.x < 64) gemm_body(W0, x0, b0, o0, 4096, blockIdx.x * 64);
  else                 gemm_body(W1, x1, b1, o1, 4096, (blockIdx.x - 64) * 64);
}

// ---------------- persistent dataflow sequential kernel ---------------------
// 256 blocks x 256 threads; wave w of block b owns column j = b*4+w.
__global__ __launch_bounds__(256, 1) void seq_kernel(
    const float* __restrict__ enc_Whh, const float* __restrict__ dec_Whh,
    const float* __restrict__ W_mean, const float* __restrict__ b_mean,
    const float* __restrict__ W_var, const float* __restrict__ b_var,
    const float* __restrict__ W_l2h, const float* __restrict__ b_l2h,
    const float* __restrict__ eps, float* __restrict__ ws, float* __restrict__ dout) {
  __shared__ float hs[Hd];
  __shared__ float lat[288];
  const int tid = threadIdx.x;
  const int lane = tid & 63;
  const int j = blockIdx.x * 4 + (tid >> 6);

  unsigned long long* hb = (unsigned long long*)(ws + OFF_HBUF);
  unsigned long long* mf = (unsigned long long*)(ws + OFF_MEANF);
  const float* Genc = ws + OFF_GENC;
  const float* Gdec = ws + OFF_GDEC;
  float* h_all = ws + OFF_HALL;

  // ---- recurrent weights -> pinned registers ----
  float we[4][16], wd[4][16];
#pragma unroll
  for (int r = 0; r < 4; ++r) {
    const size_t ro = (size_t)(r * Hd + j) * Hd + lane;
#pragma unroll
    for (int i = 0; i < 16; ++i) {
      we[r][i] = enc_Whh[ro + 64 * i];
      wd[r][i] = dec_Whh[ro + 64 * i];
    }
  }
#pragma unroll
  for (int r = 0; r < 4; ++r)
#pragma unroll
    for (int i = 0; i < 16; ++i) {
      asm volatile("" : "+v"(we[r][i]));
      asm volatile("" : "+v"(wd[r][i]));
    }

  // ---- encoder ----
  float c_reg = 0.f;
  for (int t = 0; t < Td; ++t) {
    stage_h(hb + (size_t)t * 1024, hs, tid);
    float p0 = 0.f, p1 = 0.f, p2 = 0.f, p3 = 0.f;
#pragma unroll
    for (int i = 0; i < 16; ++i) {
      float hv = hs[lane + 64 * i];
      p0 = fmaf(we[0][i], hv, p0);
      p1 = fmaf(we[1][i], hv, p1);
      p2 = fmaf(we[2][i], hv, p2);
      p3 = fmaf(we[3][i], hv, p3);
    }
#pragma unroll
    for (int off = 32; off; off >>= 1) {
      p0 += __shfl_xor(p0, off, 64); p1 += __shfl_xor(p1, off, 64);
      p2 += __shfl_xor(p2, off, 64); p3 += __shfl_xor(p3, off, 64);
    }
    float gi = Genc[t * 4096 + j] + p0;
    float gf = Genc[t * 4096 + Hd + j] + p1;
    float gg = Genc[t * 4096 + 2 * Hd + j] + p2;
    float go = Genc[t * 4096 + 3 * Hd + j] + p3;
    c_reg = sigm(gf) * c_reg + sigm(gi) * tanhf(gg);
    float hval = sigm(go) * tanhf(c_reg);
    if (lane == 0) st_flagged(hb + (size_t)(t + 1) * 1024 + j, hval);
  }

  // ---- final encoder h ----
  stage_h(hb + (size_t)64 * 1024, hs, tid);

  // ---- mean / logvar (blocks owning j<512) ----
  if (j < 512) {
    const float* Wrow = (j < 256) ? (W_mean + (size_t)j * Hd) : (W_var + (size_t)(j - 256) * Hd);
    float p = 0.f;
#pragma unroll
    for (int i = 0; i < 16; ++i) p = fmaf(Wrow[lane + 64 * i], hs[lane + 64 * i], p);
#pragma unroll
    for (int off = 32; off; off >>= 1) p += __shfl_xor(p, off, 64);
    if (lane == 0) {
      float v = p + ((j < 256) ? b_mean[j] : b_var[j - 256]);
      st_flagged(mf + j, v);
      dout[(j < 256) ? (2048064 + j) : (2048320 + (j - 256))] = v;
    }
  }

  // ---- poll mean/logvar, build [latent | tense] in LDS ----
  {
    float m  = ld_spin(mf + tid);
    float lv = ld_spin(mf + tid + 256);
    lat[tid] = m + eps[tid] * expf(0.5f * lv);
    if (tid < 32) lat[256 + tid] = ws[OFF_TEN + tid];
    __syncthreads();
  }

  // ---- dec_h0[j] = W_l2h[j]·[latent|tense] + b ----
  {
    float p = 0.f;
#pragma unroll
    for (int m = 0; m < 4; ++m)
      p = fmaf(W_l2h[(size_t)j * 288 + lane + 64 * m], lat[lane + 64 * m], p);
    if (lane < 32) p = fmaf(W_l2h[(size_t)j * 288 + 256 + lane], lat[256 + lane], p);
#pragma unroll
    for (int off = 32; off; off >>= 1) p += __shfl_xor(p, off, 64);
    if (lane == 0) st_flagged(hb + (size_t)65 * 1024 + j, p + b_l2h[j]);
  }

  // ---- decoder ----
  c_reg = 0.f;
  for (int t = 0; t < Td; ++t) {
    stage_h(hb + (size_t)(65 + t) * 1024, hs, tid);
    float p0 = 0.f, p1 = 0.f, p2 = 0.f, p3 = 0.f;
#pragma unroll
    for (int i = 0; i < 16; ++i) {
      float hv = hs[lane + 64 * i];
      p0 = fmaf(wd[0][i], hv, p0);
      p1 = fmaf(wd[1][i], hv, p1);
      p2 = fmaf(wd[2][i], hv, p2);
      p3 = fmaf(wd[3][i], hv, p3);
    }
#pragma unroll
    for (int off = 32; off; off >>= 1) {
      p0 += __shfl_xor(p0, off, 64); p1 += __shfl_xor(p1, off, 64);
      p2 += __shfl_xor(p2, off, 64); p3 += __shfl_xor(p3, off, 64);
    }
    float gi = Gdec[t * 4096 + j] + p0;
    float gf = Gdec[t * 4096 + Hd + j] + p1;
    float gg = Gdec[t * 4096 + 2 * Hd + j] + p2;
    float go = Gdec[t * 4096 + 3 * Hd + j] + p3;
    c_reg = sigm(gf) * c_reg + sigm(gi) * tanhf(gg);
    float hval = sigm(go) * tanhf(c_reg);
    if (lane == 0) {
      st_flagged(hb + (size_t)(66 + t) * 1024 + j, hval);
      h_all[(size_t)t * Hd + j] = hval;
    }
  }
}

// ---------------- per-row max/argmax/log-sum-exp over vocab ------------------
__global__ __launch_bounds__(512) void rowstats_kernel(const float* __restrict__ logits,
                                                       float* __restrict__ rmax,
                                                       float* __restrict__ rlse,
                                                       float* __restrict__ pred) {
  int t = blockIdx.x, tid = threadIdx.x;
  __shared__ float sm[512];
  __shared__ int si[512];
  float m = -INFINITY; int mi = 0x7fffffff;
  for (int v = tid; v < Vd; v += 512) {
    float x = logits[(size_t)t * Vd + v];
    if (x > m) { m = x; mi = v; }
  }
  sm[tid] = m; si[tid] = mi;
  __syncthreads();
  for (int s = 256; s > 0; s >>= 1) {
    if (tid < s) {
      float om = sm[tid + s]; int oi = si[tid + s];
      if (om > sm[tid] || (om == sm[tid] && oi < si[tid])) { sm[tid] = om; si[tid] = oi; }
    }
    __syncthreads();
  }
  float rm = sm[0]; int ri = si[0];
  __syncthreads();
  float s = 0.f;
  for (int v = tid; v < Vd; v += 512) s += expf(logits[(size_t)t * Vd + v] - rm);
  sm[tid] = s;
  __syncthreads();
  for (int st = 256; st > 0; st >>= 1) {
    if (tid < st) sm[tid] += sm[tid + st];
    __syncthreads();
  }
  if (tid == 0) { rmax[t] = rm; rlse[t] = logf(sm[0]); pred[t] = (float)ri; }
}

// ---------------- in-place log_softmax finalize ------------------------------
__global__ void finalize_kernel(float* __restrict__ out, const float* __restrict__ rmax,
                                const float* __restrict__ rlse) {
  int i = blockIdx.x * blockDim.x + threadIdx.x;   // over 512000 float4s
  if (i < 512000) {
    int base = i * 4;
    int t = base / Vd;
    float m = rmax[t] + rlse[t];
    float4* p = (float4*)(out + 64 + base);
    float4 v = *p;
    v.x -= m; v.y -= m; v.z -= m; v.w -= m;
    *p = v;
  }
}

extern "C" void kernel_launch(void* const* d_in, const int* in_sizes, int n_in,
                              void* d_out, int out_size, void* d_ws, size_t ws_size,
                              hipStream_t stream) {
  (void)in_sizes; (void)n_in; (void)out_size; (void)ws_size;
  const int* word       = (const int*)d_in[0];
  const int* tense      = (const int*)d_in[1];
  const float* tense_emb = (const float*)d_in[3];
  const float* enc_emb   = (const float*)d_in[4];
  const float* enc_Wih   = (const float*)d_in[5];
  const float* enc_Whh   = (const float*)d_in[6];
  const float* enc_bih   = (const float*)d_in[7];
  const float* enc_bhh   = (const float*)d_in[8];
  const float* W_mean    = (const float*)d_in[9];
  const float* b_mean    = (const float*)d_in[10];
  const float* W_var     = (const float*)d_in[11];
  const float* b_var     = (const float*)d_in[12];
  const float* W_l2h     = (const float*)d_in[13];
  const float* b_l2h     = (const float*)d_in[14];
  const float* dec_emb   = (const float*)d_in[15];
  const float* dec_Wih   = (const float*)d_in[16];
  const float* dec_Whh   = (const float*)d_in[17];
  const float* dec_bih   = (const float*)d_in[18];
  const float* dec_bhh   = (const float*)d_in[19];
  const float* W_out     = (const float*)d_in[20];
  const float* b_out     = (const float*)d_in[21];
  const float* eps       = (const float*)d_in[22];
  float* out = (float*)d_out;
  float* ws  = (float*)d_ws;

  prep_kernel<<<512, 256, 0, stream>>>(word, tense, tense_emb, enc_emb, dec_emb,
                                       enc_bih, enc_bhh, dec_bih, dec_bhh, ws);
  gemm_dual_kernel<<<128, 256, 0, stream>>>(enc_Wih, ws + OFF_ENCX, ws + OFF_BSE, ws + OFF_GENC,
                                            dec_Wih, ws + OFF_DECX, ws + OFF_BSD, ws + OFF_GDEC);
  {
    const float* a0 = enc_Whh; const float* a1 = dec_Whh;
    const float* a2 = W_mean;  const float* a3 = b_mean;
    const float* a4 = W_var;   const float* a5 = b_var;
    const float* a6 = W_l2h;   const float* a7 = b_l2h;
    const float* a8 = eps;     float* a9 = ws; float* a10 = out;
    void* args[] = {&a0, &a1, &a2, &a3, &a4, &a5, &a6, &a7, &a8, &a9, &a10};
    hipLaunchCooperativeKernel((void*)seq_kernel, dim3(256), dim3(256), args, 0, stream);
  }
  gemm_kernel<<<500, 256, 0, stream>>>(W_out, ws + OFF_HALL, b_out, out + 64, 32000);
  rowstats_kernel<<<64, 512, 0, stream>>>(out + 64, ws + OFF_RMAX, ws + OFF_RLSE, out);
  finalize_kernel<<<2000, 256, 0, stream>>>(out, ws + OFF_RMAX, ws + OFF_RLSE);
}

// Round 3
// 599.058 us; speedup vs baseline: 10.2931x; 1.0841x over previous
//
#include <hip/hip_runtime.h>
#include <math.h>

#define Hd 1024
#define Td 64
#define Vd 32000

// ---- workspace float offsets ----
static const size_t OFF_ENCX  = 0;         // 64*1024
static const size_t OFF_DECX  = 65536;     // 64*1024
static const size_t OFF_GENC  = 131072;    // 64*4096
static const size_t OFF_GDEC  = 393216;    // 64*4096
static const size_t OFF_BSE   = 655360;    // 4096
static const size_t OFF_BSD   = 659456;    // 4096
static const size_t OFF_TEN   = 663552;    // 32
static const size_t OFF_HALL  = 663584;    // 64*1024
static const size_t OFF_HBUF  = 729248;    // 130*1024 float2 (flagged h exchange)
static const size_t OFF_MEANF = 995488;    // 512 float2 (flagged mean/logvar)

__device__ __forceinline__ float fsigm(float x) {
  return __fdividef(1.f, 1.f + __expf(-x));
}
__device__ __forceinline__ float ftanh(float x) {
  return 1.f - __fdividef(2.f, __expf(2.f * x) + 1.f);
}

__device__ __forceinline__ void st_flag(unsigned long long* p, float v) {
  unsigned long long u = 0x3f80000000000000ull | (unsigned long long)__float_as_uint(v);
  __hip_atomic_store(p, u, __ATOMIC_RELAXED, __HIP_MEMORY_SCOPE_AGENT);
}

// coalesced 16B coherent poll load (two {value,flag} pairs)
__device__ __forceinline__ float4 poll16(const float2* p) {
  float4 a;
  asm volatile("global_load_dwordx4 %0, %1, off sc0 sc1\n\ts_waitcnt vmcnt(0)"
               : "=&v"(a) : "v"(p) : "memory");
  return a;
}

// stage 1024 flagged entries (512 threads, 2 per thread) into LDS
__device__ __forceinline__ void stage1024(const float2* base, float* hs, int tid) {
  const float2* p = base + 2 * tid;
  float4 a = poll16(p);
  while (__float_as_uint(a.y) != 0x3f800000u || __float_as_uint(a.w) != 0x3f800000u) {
    __builtin_amdgcn_s_sleep(1);
    a = poll16(p);
  }
  __syncthreads();                       // prior readers of hs done
  ((float2*)hs)[tid] = make_float2(a.x, a.z);
  __syncthreads();
}

// 16 weight loads (stride 256B) through one opaque asm block -> forced VGPR residency
__device__ __forceinline__ void gload16(const float* base, float* d) {
  asm volatile(
      "global_load_dword %0, %16, off\n\t"
      "global_load_dword %1, %16, off offset:256\n\t"
      "global_load_dword %2, %16, off offset:512\n\t"
      "global_load_dword %3, %16, off offset:768\n\t"
      "global_load_dword %4, %16, off offset:1024\n\t"
      "global_load_dword %5, %16, off offset:1280\n\t"
      "global_load_dword %6, %16, off offset:1536\n\t"
      "global_load_dword %7, %16, off offset:1792\n\t"
      "global_load_dword %8, %16, off offset:2048\n\t"
      "global_load_dword %9, %16, off offset:2304\n\t"
      "global_load_dword %10, %16, off offset:2560\n\t"
      "global_load_dword %11, %16, off offset:2816\n\t"
      "global_load_dword %12, %16, off offset:3072\n\t"
      "global_load_dword %13, %16, off offset:3328\n\t"
      "global_load_dword %14, %16, off offset:3584\n\t"
      "global_load_dword %15, %16, off offset:3840\n\t"
      "s_waitcnt vmcnt(0)"
      : "=&v"(d[0]), "=&v"(d[1]), "=&v"(d[2]), "=&v"(d[3]),
        "=&v"(d[4]), "=&v"(d[5]), "=&v"(d[6]), "=&v"(d[7]),
        "=&v"(d[8]), "=&v"(d[9]), "=&v"(d[10]), "=&v"(d[11]),
        "=&v"(d[12]), "=&v"(d[13]), "=&v"(d[14]), "=&v"(d[15])
      : "v"(base));
}

// ---------------- prep: gathers, bias sums, flag-buffer init ----------------
__global__ void prep_kernel(const int* __restrict__ word, const int* __restrict__ tense,
                            const float* __restrict__ tense_emb,
                            const float* __restrict__ enc_emb, const float* __restrict__ dec_emb,
                            const float* __restrict__ enc_bih, const float* __restrict__ enc_bhh,
                            const float* __restrict__ dec_bih, const float* __restrict__ dec_bhh,
                            float* __restrict__ ws) {
  int gid = blockIdx.x * blockDim.x + threadIdx.x;
  int gsz = gridDim.x * blockDim.x;
  int tens = tense[0];
  for (int i = gid; i < Td * Hd; i += gsz) {
    int t = i >> 10, hh = i & 1023;
    ws[OFF_ENCX + i] = enc_emb[(size_t)word[t] * Hd + hh];
    int tok = (t == 0) ? 0 : word[t - 1];        // SOS = 0
    float v = dec_emb[(size_t)tok * Hd + hh];
    ws[OFF_DECX + i] = v > 0.f ? v : 0.f;        // relu
  }
  for (int i = gid; i < 4096; i += gsz) {
    ws[OFF_BSE + i] = enc_bih[i] + enc_bhh[i];
    ws[OFF_BSD + i] = dec_bih[i] + dec_bhh[i];
  }
  for (int i = gid; i < 32; i += gsz) ws[OFF_TEN + i] = tense_emb[tens * 32 + i];
  float2* hb = (float2*)(ws + OFF_HBUF);
  for (int i = gid; i < 130 * 1024; i += gsz) {
    int s = i >> 10, j = i & 1023;
    float2 v;
    if (s == 0) {
      v.x = (j < Hd - 32) ? 0.f : tense_emb[tens * 32 + (j - (Hd - 32))];
      v.y = 1.0f;
    } else {
      v.x = 0.f; v.y = 0.f;
    }
    hb[i] = v;
  }
  float2* mf = (float2*)(ws + OFF_MEANF);
  for (int i = gid; i < 512; i += gsz) mf[i] = make_float2(0.f, 0.f);
}

// ---------------- fp32 GEMM body: out[t][r] = x[t]·W[r] + bias[r] -----------
__device__ __forceinline__ void gemm_body(const float* __restrict__ W,
                                          const float* __restrict__ x,
                                          const float* __restrict__ bias,
                                          float* __restrict__ out, int R, int rbase) {
  __shared__ float xs[64][65];
  __shared__ float wsh[64][65];
  const int tid = threadIdx.x;
  const int a = tid >> 4;
  const int b = tid & 15;
  const int srow = tid >> 2;
  const int scol = (tid & 3) * 16;
  float acc[4][4];
#pragma unroll
  for (int i = 0; i < 4; ++i)
#pragma unroll
    for (int q = 0; q < 4; ++q) acc[i][q] = 0.f;

  for (int kc = 0; kc < 1024; kc += 64) {
    const float4* gx = (const float4*)(x + (size_t)srow * 1024 + kc + scol);
    const float4* gw = (const float4*)(W + (size_t)(rbase + srow) * 1024 + kc + scol);
    float4 vx0 = gx[0], vx1 = gx[1], vx2 = gx[2], vx3 = gx[3];
    float4 vw0 = gw[0], vw1 = gw[1], vw2 = gw[2], vw3 = gw[3];
    __syncthreads();
    float* xr = &xs[srow][scol];
    xr[0]=vx0.x; xr[1]=vx0.y; xr[2]=vx0.z; xr[3]=vx0.w;
    xr[4]=vx1.x; xr[5]=vx1.y; xr[6]=vx1.z; xr[7]=vx1.w;
    xr[8]=vx2.x; xr[9]=vx2.y; xr[10]=vx2.z; xr[11]=vx2.w;
    xr[12]=vx3.x; xr[13]=vx3.y; xr[14]=vx3.z; xr[15]=vx3.w;
    float* wr = &wsh[srow][scol];
    wr[0]=vw0.x; wr[1]=vw0.y; wr[2]=vw0.z; wr[3]=vw0.w;
    wr[4]=vw1.x; wr[5]=vw1.y; wr[6]=vw1.z; wr[7]=vw1.w;
    wr[8]=vw2.x; wr[9]=vw2.y; wr[10]=vw2.z; wr[11]=vw2.w;
    wr[12]=vw3.x; wr[13]=vw3.y; wr[14]=vw3.z; wr[15]=vw3.w;
    __syncthreads();
#pragma unroll 8
    for (int kk = 0; kk < 64; ++kk) {
      float xv[4], wv[4];
#pragma unroll
      for (int i = 0; i < 4; ++i) xv[i] = xs[a * 4 + i][kk];
#pragma unroll
      for (int q = 0; q < 4; ++q) wv[q] = wsh[b * 4 + q][kk];
#pragma unroll
      for (int i = 0; i < 4; ++i)
#pragma unroll
        for (int q = 0; q < 4; ++q) acc[i][q] = fmaf(xv[i], wv[q], acc[i][q]);
    }
  }
#pragma unroll
  for (int i = 0; i < 4; ++i) {
    int t = a * 4 + i;
#pragma unroll
    for (int q = 0; q < 4; ++q) {
      int r = rbase + b * 4 + q;
      out[(size_t)t * R + r] = acc[i][q] + bias[r];
    }
  }
}

__global__ __launch_bounds__(256) void gemm_kernel(const float* __restrict__ W,
                                                   const float* __restrict__ x,
                                                   const float* __restrict__ bias,
                                                   float* __restrict__ out, int R) {
  gemm_body(W, x, bias, out, R, blockIdx.x * 64);
}

__global__ __launch_bounds__(256) void gemm_dual_kernel(
    const float* __restrict__ W0, const float* __restrict__ x0,
    const float* __restrict__ b0, float* __restrict__ o0,
    const float* __restrict__ W1, const float* __restrict__ x1,
    const float* __restrict__ b1, float* __restrict__ o1) {
  if (blockIdx.x < 64) gemm_body(W0, x0, b0, o0, 4096, blockIdx.x * 64);
  else                 gemm_body(W1, x1, b1, o1, 4096, (blockIdx.x - 64) * 64);
}

// ---------------- persistent dataflow sequential kernel ---------------------
// 128 blocks x 512 threads (8 waves); wave w of block b owns column j = b*8+w.
__global__ __launch_bounds__(512, 2) void seq_kernel(
    const float* __restrict__ enc_Whh, const float* __restrict__ dec_Whh,
    const float* __restrict__ W_mean, const float* __restrict__ b_mean,
    const float* __restrict__ W_var, const float* __restrict__ b_var,
    const float* __restrict__ W_l2h, const float* __restrict__ b_l2h,
    const float* __restrict__ eps, float* __restrict__ ws, float* __restrict__ dout) {
  __shared__ float hs[Hd];
  __shared__ float sm2[512];
  __shared__ float lat[288];
  const int tid = threadIdx.x;
  const int lane = tid & 63;
  const int wid = tid >> 6;
  const int j = blockIdx.x * 8 + wid;          // 0..1023

  float2* hb = (float2*)(ws + OFF_HBUF);
  unsigned long long* hbq = (unsigned long long*)(ws + OFF_HBUF);
  unsigned long long* mfq = (unsigned long long*)(ws + OFF_MEANF);
  const float* Genc = ws + OFF_GENC;
  const float* Gdec = ws + OFF_GDEC;
  float* h_all = ws + OFF_HALL;

  // ---- recurrent weights -> registers (opaque loads, not rematerializable) ----
  float we[4][16], wd[4][16];
#pragma unroll
  for (int r = 0; r < 4; ++r) {
    const size_t ro = (size_t)(r * Hd + j) * Hd + lane;
    gload16(enc_Whh + ro, we[r]);
    gload16(dec_Whh + ro, wd[r]);
  }

  // ---- encoder ----
  float c_reg = 0.f;
  for (int t = 0; t < Td; ++t) {
    // prefetch gate biases (complete under the poll's vmcnt(0))
    float gb0 = Genc[t * 4096 + j];
    float gb1 = Genc[t * 4096 + 1024 + j];
    float gb2 = Genc[t * 4096 + 2048 + j];
    float gb3 = Genc[t * 4096 + 3072 + j];
    stage1024(hb + (size_t)t * 1024, hs, tid);
    float p0 = 0.f, p1 = 0.f, p2 = 0.f, p3 = 0.f;
#pragma unroll
    for (int i = 0; i < 16; ++i) {
      float hv = hs[lane + 64 * i];
      p0 = fmaf(we[0][i], hv, p0);
      p1 = fmaf(we[1][i], hv, p1);
      p2 = fmaf(we[2][i], hv, p2);
      p3 = fmaf(we[3][i], hv, p3);
    }
#pragma unroll
    for (int off = 32; off; off >>= 1) {
      p0 += __shfl_xor(p0, off, 64); p1 += __shfl_xor(p1, off, 64);
      p2 += __shfl_xor(p2, off, 64); p3 += __shfl_xor(p3, off, 64);
    }
    float gi = gb0 + p0, gf = gb1 + p1, gg = gb2 + p2, go = gb3 + p3;
    c_reg = fsigm(gf) * c_reg + fsigm(gi) * ftanh(gg);
    float hval = fsigm(go) * ftanh(c_reg);
    if (lane == 0) st_flag(hbq + (size_t)(t + 1) * 1024 + j, hval);
  }

  // ---- final encoder h ----
  stage1024(hb + (size_t)64 * 1024, hs, tid);

  // ---- mean / logvar (waves owning j<512) ----
  if (j < 512) {
    const float* Wrow = (j < 256) ? (W_mean + (size_t)j * Hd) : (W_var + (size_t)(j - 256) * Hd);
    float p = 0.f;
#pragma unroll
    for (int i = 0; i < 16; ++i) p = fmaf(Wrow[lane + 64 * i], hs[lane + 64 * i], p);
#pragma unroll
    for (int off = 32; off; off >>= 1) p += __shfl_xor(p, off, 64);
    if (lane == 0) {
      float v = p + ((j < 256) ? b_mean[j] : b_var[j - 256]);
      st_flag(mfq + j, v);
      dout[(j < 256) ? (2048064 + j) : (2048320 + (j - 256))] = v;
    }
  }

  // ---- poll mean/logvar, build [latent | tense] ----
  if (tid < 256) {
    const float2* p = (const float2*)mfq + 2 * tid;
    float4 a = poll16(p);
    while (__float_as_uint(a.y) != 0x3f800000u || __float_as_uint(a.w) != 0x3f800000u) {
      __builtin_amdgcn_s_sleep(1);
      a = poll16(p);
    }
    sm2[2 * tid] = a.x; sm2[2 * tid + 1] = a.z;
  }
  __syncthreads();
  if (tid < 256)      lat[tid] = sm2[tid] + eps[tid] * __expf(0.5f * sm2[tid + 256]);
  else if (tid < 288) lat[tid] = ws[OFF_TEN + tid - 256];
  __syncthreads();

  // ---- dec_h0[j] = W_l2h[j]·[latent|tense] + b ----
  {
    const float* Wr = W_l2h + (size_t)j * 288;
    float p = fmaf(Wr[lane], lat[lane], 0.f);
    p = fmaf(Wr[lane + 64], lat[lane + 64], p);
    p = fmaf(Wr[lane + 128], lat[lane + 128], p);
    p = fmaf(Wr[lane + 192], lat[lane + 192], p);
    if (lane < 32) p = fmaf(Wr[lane + 256], lat[lane + 256], p);
#pragma unroll
    for (int off = 32; off; off >>= 1) p += __shfl_xor(p, off, 64);
    if (lane == 0) st_flag(hbq + (size_t)65 * 1024 + j, p + b_l2h[j]);
  }

  // ---- decoder ----
  c_reg = 0.f;
  for (int t = 0; t < Td; ++t) {
    float gb0 = Gdec[t * 4096 + j];
    float gb1 = Gdec[t * 4096 + 1024 + j];
    float gb2 = Gdec[t * 4096 + 2048 + j];
    float gb3 = Gdec[t * 4096 + 3072 + j];
    stage1024(hb + (size_t)(65 + t) * 1024, hs, tid);
    float p0 = 0.f, p1 = 0.f, p2 = 0.f, p3 = 0.f;
#pragma unroll
    for (int i = 0; i < 16; ++i) {
      float hv = hs[lane + 64 * i];
      p0 = fmaf(wd[0][i], hv, p0);
      p1 = fmaf(wd[1][i], hv, p1);
      p2 = fmaf(wd[2][i], hv, p2);
      p3 = fmaf(wd[3][i], hv, p3);
    }
#pragma unroll
    for (int off = 32; off; off >>= 1) {
      p0 += __shfl_xor(p0, off, 64); p1 += __shfl_xor(p1, off, 64);
      p2 += __shfl_xor(p2, off, 64); p3 += __shfl_xor(p3, off, 64);
    }
    float gi = gb0 + p0, gf = gb1 + p1, gg = gb2 + p2, go = gb3 + p3;
    c_reg = fsigm(gf) * c_reg + fsigm(gi) * ftanh(gg);
    float hval = fsigm(go) * ftanh(c_reg);
    if (lane == 0) {
      st_flag(hbq + (size_t)(66 + t) * 1024 + j, hval);
      h_all[(size_t)t * Hd + j] = hval;
    }
  }
}

// ---------------- fused per-row max/argmax/LSE + normalize -------------------
__global__ __launch_bounds__(1024) void logsm_kernel(float* __restrict__ out) {
  const int t = blockIdx.x, tid = threadIdx.x;
  float* row = out + 64 + (size_t)t * Vd;
  __shared__ float sm[1024];
  __shared__ int si[1024];
  float m = -INFINITY; int mi = 0;
  for (int v = tid; v < Vd; v += 1024) {
    float x = row[v];
    if (x > m) { m = x; mi = v; }
  }
  sm[tid] = m; si[tid] = mi;
  __syncthreads();
  for (int s = 512; s > 0; s >>= 1) {
    if (tid < s) {
      float om = sm[tid + s]; int oi = si[tid + s];
      if (om > sm[tid] || (om == sm[tid] && oi < si[tid])) { sm[tid] = om; si[tid] = oi; }
    }
    __syncthreads();
  }
  float rm = sm[0]; int ri = si[0];
  __syncthreads();
  float s = 0.f;
  for (int v = tid; v < Vd; v += 1024) s += __expf(row[v] - rm);
  sm[tid] = s;
  __syncthreads();
  for (int st = 512; st > 0; st >>= 1) {
    if (tid < st) sm[tid] += sm[tid + st];
    __syncthreads();
  }
  float corr = rm + logf(sm[0]);
  float4* r4 = (float4*)row;
  for (int i = tid; i < Vd / 4; i += 1024) {
    float4 v = r4[i];
    v.x -= corr; v.y -= corr; v.z -= corr; v.w -= corr;
    r4[i] = v;
  }
  if (tid == 0) out[t] = (float)ri;
}

extern "C" void kernel_launch(void* const* d_in, const int* in_sizes, int n_in,
                              void* d_out, int out_size, void* d_ws, size_t ws_size,
                              hipStream_t stream) {
  (void)in_sizes; (void)n_in; (void)out_size; (void)ws_size;
  const int* word       = (const int*)d_in[0];
  const int* tense      = (const int*)d_in[1];
  const float* tense_emb = (const float*)d_in[3];
  const float* enc_emb   = (const float*)d_in[4];
  const float* enc_Wih   = (const float*)d_in[5];
  const float* enc_Whh   = (const float*)d_in[6];
  const float* enc_bih   = (const float*)d_in[7];
  const float* enc_bhh   = (const float*)d_in[8];
  const float* W_mean    = (const float*)d_in[9];
  const float* b_mean    = (const float*)d_in[10];
  const float* W_var     = (const float*)d_in[11];
  const float* b_var     = (const float*)d_in[12];
  const float* W_l2h     = (const float*)d_in[13];
  const float* b_l2h     = (const float*)d_in[14];
  const float* dec_emb   = (const float*)d_in[15];
  const float* dec_Wih   = (const float*)d_in[16];
  const float* dec_Whh   = (const float*)d_in[17];
  const float* dec_bih   = (const float*)d_in[18];
  const float* dec_bhh   = (const float*)d_in[19];
  const float* W_out     = (const float*)d_in[20];
  const float* b_out     = (const float*)d_in[21];
  const float* eps       = (const float*)d_in[22];
  float* out = (float*)d_out;
  float* ws  = (float*)d_ws;

  prep_kernel<<<512, 256, 0, stream>>>(word, tense, tense_emb, enc_emb, dec_emb,
                                       enc_bih, enc_bhh, dec_bih, dec_bhh, ws);
  gemm_dual_kernel<<<128, 256, 0, stream>>>(enc_Wih, ws + OFF_ENCX, ws + OFF_BSE, ws + OFF_GENC,
                                            dec_Wih, ws + OFF_DECX, ws + OFF_BSD, ws + OFF_GDEC);
  seq_kernel<<<128, 512, 0, stream>>>(enc_Whh, dec_Whh, W_mean, b_mean, W_var, b_var,
                                      W_l2h, b_l2h, eps, ws, out);
  gemm_kernel<<<500, 256, 0, stream>>>(W_out, ws + OFF_HALL, b_out, out + 64, 32000);
  logsm_kernel<<<64, 1024, 0, stream>>>(out);
}